// Round 9
// baseline (98.512 us; speedup 1.0000x reference)
//
#include <hip/hip_runtime.h>

// ResidualBlock2 (AdderNet): two adder-convs + BN + ReLU + residual.
// N=32, C=32, H=W=32, K=3. No multiplies -> no MFMA; pure VALU
// (2 instr per |x-w|; floor ~7.7us/conv = 576 VALU cyc/SIMD/ci).
// R9: in-block ci-split. 4 waves/block compute the SAME 4rowx32colx8co
// tile, each over its own 8-ci slice (lane = 4 cols x 4 co = 16 acc);
// LDS cross-wave reduce at the end. Keeps 16 waves/CU (=4/SIMD, R8's
// proven occupancy lever) while amortizing broadcast weight reads over
// 4x more outputs: LDS/CU/ci 2560 (R8) -> ~2700/4... = 16w x 168cyc but
// only 8 ci/wave => 21.5K cyc/conv vs VALU 18.4K: balanced.

#define QSCALE (2.5f / 127.f)

__device__ __forceinline__ float quantf(float w) {
  float v = rintf(w * (1.0f / QSCALE));     // round-half-even = jnp.round
  v = fminf(fmaxf(v, -127.f), 127.f);
  return v * QSCALE;
}

// quantize + pack: WQ[(ci*9+tap)*32 + co] = quant(w[co][ci*9+tap])
__global__ __launch_bounds__(256) void quant_k(const float* __restrict__ w1,
                                               const float* __restrict__ w2,
                                               float* __restrict__ q1,
                                               float* __restrict__ q2) {
  int i = blockIdx.x * 256 + threadIdx.x;
  if (i >= 18432) return;
  const float* w = (i < 9216) ? w1 : w2;
  float* dst = (i < 9216) ? q1 : q2;
  int j = (i < 9216) ? i : i - 9216;
  int co = j / 288;
  int r = j - co * 288;                     // r = ci*9 + tap
  dst[r * 32 + co] = quantf(w[j]);
}

// Grid 1024 = 32 n x 8 rowgroups(4 rows) x 4 co-octs. Block 256 thr =
// 4 waves; wave wv sums ci 8wv..8wv+7 for the whole tile. Lane l:
// q8=l&7 (cols 4q8..+3), r4=(l>>3)&3 (row h0+r4), hh=l>>5 (co 4hh..+3).
// 4 blocks/CU (LDS 37KB) => 16 waves/CU = 4/SIMD.
template <bool AFFINE>
__global__ __launch_bounds__(256, 4) void conv_k(
    const float* __restrict__ in,       // [32][32][32][32] conv input
    const float* __restrict__ wq,       // packed [288][32] this conv
    const float* __restrict__ ps_prev,  // [32][256] prev partial sums (or null)
    const float* __restrict__ pq_prev,  // [32][256] prev partial sumsq
    const float* __restrict__ wq_prev,  // packed prev weights (for wb)
    const float* __restrict__ gprev,    // prev gamma
    const float* __restrict__ bprev,    // prev beta
    float* __restrict__ outb,           // raw conv out
    float* __restrict__ ps_out,         // [32][256] idx: co*256 + n*8 + rg
    float* __restrict__ pq_out) {
  __shared__ __align__(16) float smem[6912];  // x tile / BN scratch / reduce
  __shared__ __align__(16) float wls[2304];   // [ci*9+tap][8 co]
  __shared__ float abuf[32], bbuf[32];

  const int tid = threadIdx.x;
  const int blk = blockIdx.x;
  const int n = blk >> 5;
  const int rg = (blk >> 2) & 7;
  const int oc = blk & 3;
  const int h0 = rg << 2;

  if (AFFINE) {
    // Redundant per-block BN1 fold: a=g/sqrt(var+eps), b=beta+wb-a*mu.
    float* r2a = smem; float* r2b = smem + 256; float* r2c = smem + 512;
    const int c = tid & 31, ch = tid >> 5;
    float s = 0.f, q = 0.f;
    #pragma unroll 4
    for (int k = 0; k < 32; ++k) {
      s += ps_prev[c * 256 + ch * 32 + k];
      q += pq_prev[c * 256 + ch * 32 + k];
    }
    float wbp = 0.f;
    #pragma unroll 4
    for (int u = 0; u < 36; ++u) wbp += fabsf(wq_prev[(ch * 36 + u) * 32 + c]);
    r2a[c * 8 + ch] = s; r2b[c * 8 + ch] = q; r2c[c * 8 + ch] = wbp;
    __syncthreads();
    if (tid < 32) {
      double S = 0.0, Q = 0.0; float W = 0.f;
      #pragma unroll
      for (int k = 0; k < 8; ++k) {
        S += (double)r2a[tid * 8 + k];
        Q += (double)r2b[tid * 8 + k];
        W += r2c[tid * 8 + k];
      }
      const double M = 32768.0;
      const double mu = S / M;
      const double var = Q / M - mu * mu;
      const double inv = 1.0 / sqrt(var + 1e-5);
      const double g = (double)gprev[tid];
      abuf[tid] = (float)(g * inv);
      bbuf[tid] = (float)((double)bprev[tid] + (double)(W * (1.f / 288.f)) - g * inv * mu);
    }
    __syncthreads();
  }

  // stage weights: wls[(ci*9+tap)*8 + j] = wq[(ci*9+tap)*32 + oc*8 + j]
  for (int i = tid; i < 2304; i += 256)
    wls[i] = wq[(i >> 3) * 32 + oc * 8 + (i & 7)];
  // stage x: smem[ci*216 + r*36 + c]; r=0..5 <-> row h0-1+r; c <-> col c-1
  for (int i = tid; i < 6912; i += 256) {
    const int ci = i / 216;
    const int rem = i - ci * 216;
    const int r = rem / 36, c = rem - r * 36;
    const int h = h0 - 1 + r, wcol = c - 1;
    float v = 0.f;
    if ((unsigned)h < 32u && (unsigned)wcol < 32u) {
      v = in[((n * 32 + ci) * 32 + h) * 32 + wcol];
      if (AFFINE) v = fmaxf(fmaf(abuf[ci], v, bbuf[ci]), 0.f);
    }
    smem[i] = v;
  }
  __syncthreads();

  const int l = tid & 63, wv = tid >> 6;
  const int q8 = l & 7, r4 = (l >> 3) & 3, hh = l >> 5;

  float acc[4][4];
  #pragma unroll
  for (int j = 0; j < 4; ++j)
    #pragma unroll
    for (int k = 0; k < 4; ++k) acc[j][k] = 0.f;

  const float* xpb = smem + r4 * 36 + 4 * q8;
  const float* wpb = wls + 4 * hh;

  #pragma unroll 2
  for (int c8 = 0; c8 < 8; ++c8) {
    const int ci = wv * 8 + c8;
    const float* xp = xpb + ci * 216;
    float xw[3][6];
    #pragma unroll
    for (int rr = 0; rr < 3; ++rr) {
      const float4 A = *(const float4*)(xp + rr * 36);
      const float2 B = *(const float2*)(xp + rr * 36 + 4);
      xw[rr][0] = A.x; xw[rr][1] = A.y; xw[rr][2] = A.z; xw[rr][3] = A.w;
      xw[rr][4] = B.x; xw[rr][5] = B.y;
    }
    const float* wp = wpb + ci * 72;
    #pragma unroll
    for (int kh = 0; kh < 3; ++kh) {
      #pragma unroll
      for (int kw = 0; kw < 3; ++kw) {
        const float4 W = *(const float4*)(wp + (kh * 3 + kw) * 8);
        #pragma unroll
        for (int j = 0; j < 4; ++j) {
          const float xv = xw[kh][j + kw];
          acc[j][0] += fabsf(xv - W.x);
          acc[j][1] += fabsf(xv - W.y);
          acc[j][2] += fabsf(xv - W.z);
          acc[j][3] += fabsf(xv - W.w);
        }
      }
    }
  }
  __syncthreads();   // all x reads done before reduce buffer overwrites smem

  // cross-wave reduce: red[((wv*4+j)*4+k)*64 + l] (stride-1 writes)
  float* red = smem;
  #pragma unroll
  for (int j = 0; j < 4; ++j)
    #pragma unroll
    for (int k = 0; k < 4; ++k)
      red[((wv * 4 + j) * 4 + k) * 64 + l] = acc[j][k];
  __syncthreads();

  {
    const int co = tid >> 5;                 // 0..7 local co
    const int r2 = (tid >> 3) & 3, cq = tid & 7;
    const int lidx = (co >> 2) * 32 + r2 * 8 + cq;
    const int ksub = co & 3;
    float o[4];
    #pragma unroll
    for (int j = 0; j < 4; ++j) {
      float s = 0.f;
      #pragma unroll
      for (int v2 = 0; v2 < 4; ++v2)
        s += red[((v2 * 4 + j) * 4 + ksub) * 64 + lidx];
      o[j] = -s;
    }
    const int gco = oc * 8 + co;
    float4 st; st.x = o[0]; st.y = o[1]; st.z = o[2]; st.w = o[3];
    *(float4*)&outb[((n * 32 + gco) * 32 + (h0 + r2)) * 32 + 4 * cq] = st;
    float ssum = o[0] + o[1] + o[2] + o[3];
    float qsum = o[0]*o[0] + o[1]*o[1] + o[2]*o[2] + o[3]*o[3];
    #pragma unroll
    for (int d = 1; d < 32; d <<= 1) {
      ssum += __shfl_xor(ssum, d);
      qsum += __shfl_xor(qsum, d);
    }
    if ((tid & 31) == 0) {
      ps_out[gco * 256 + n * 8 + rg] = ssum;
      pq_out[gco * 256 + n * 8 + rg] = qsum;
    }
  }
}

// ---- K4: redundant BN2 fold + relu(a2*o2 + b2 + x) ----
__global__ __launch_bounds__(256) void final_k(
    const float* __restrict__ o2, const float* __restrict__ xres,
    const float* __restrict__ ps, const float* __restrict__ pq,
    const float* __restrict__ wq2, const float* __restrict__ g2,
    const float* __restrict__ b2, float* __restrict__ out) {
  __shared__ float r2a[32][8], r2b[32][8], r2c[32][8];
  __shared__ float abuf[32], bbuf[32];
  const int tid = threadIdx.x;
  const int c = tid & 31, ch = tid >> 5;
  float s = 0.f, q = 0.f;
  #pragma unroll 4
  for (int k = 0; k < 32; ++k) {
    s += ps[c * 256 + ch * 32 + k];
    q += pq[c * 256 + ch * 32 + k];
  }
  float wbp = 0.f;
  #pragma unroll 4
  for (int u = 0; u < 36; ++u) wbp += fabsf(wq2[(ch * 36 + u) * 32 + c]);
  r2a[c][ch] = s; r2b[c][ch] = q; r2c[c][ch] = wbp;
  __syncthreads();
  if (tid < 32) {
    double S = 0.0, Q = 0.0; float W = 0.f;
    #pragma unroll
    for (int k = 0; k < 8; ++k) {
      S += (double)r2a[tid][k]; Q += (double)r2b[tid][k]; W += r2c[tid][k];
    }
    const double M = 32768.0;
    const double mu = S / M;
    const double var = Q / M - mu * mu;
    const double inv = 1.0 / sqrt(var + 1e-5);
    const double g = (double)g2[tid];
    abuf[tid] = (float)(g * inv);
    bbuf[tid] = (float)((double)b2[tid] + (double)(W * (1.f / 288.f)) - g * inv * mu);
  }
  __syncthreads();

  const int base = blockIdx.x * 512;  // float4 units; 512 x 512 = 262144
  for (int i = tid; i < 512; i += 256) {
    const int f4 = base + i;
    const int cc = (f4 >> 8) & 31;
    const float4 o = ((const float4*)o2)[f4];
    const float4 xr = ((const float4*)xres)[f4];
    const float av = abuf[cc], bv = bbuf[cc];
    float4 r;
    r.x = fmaxf(fmaf(av, o.x, bv) + xr.x, 0.f);
    r.y = fmaxf(fmaf(av, o.y, bv) + xr.y, 0.f);
    r.z = fmaxf(fmaf(av, o.z, bv) + xr.z, 0.f);
    r.w = fmaxf(fmaf(av, o.w, bv) + xr.w, 0.f);
    ((float4*)out)[f4] = r;
  }
}

extern "C" void kernel_launch(void* const* d_in, const int* in_sizes, int n_in,
                              void* d_out, int out_size, void* d_ws, size_t ws_size,
                              hipStream_t stream) {
  const float* x   = (const float*)d_in[0];
  const float* w1  = (const float*)d_in[1];
  const float* g1  = (const float*)d_in[2];
  const float* be1 = (const float*)d_in[3];
  const float* w2  = (const float*)d_in[4];
  const float* g2  = (const float*)d_in[5];
  const float* be2 = (const float*)d_in[6];
  float* ws = (float*)d_ws;

  float* WQ1 = ws;                  // 9216  (packed [288][32])
  float* WQ2 = ws + 9216;           // 9216
  float* PS1 = ws + 18432;          // [32][256] = 8192
  float* PQ1 = ws + 26624;          // 8192
  float* PS2 = ws + 34816;          // 8192
  float* PQ2 = ws + 43008;          // 8192
  float* O1  = ws + 51200;          // 1048576 (16B aligned)
  float* O2  = O1 + 1048576;        // 1048576
  float* out = (float*)d_out;

  quant_k<<<72, 256, 0, stream>>>(w1, w2, WQ1, WQ2);
  conv_k<false><<<1024, 256, 0, stream>>>(x, WQ1, nullptr, nullptr, nullptr,
                                          nullptr, nullptr, O1, PS1, PQ1);
  conv_k<true><<<1024, 256, 0, stream>>>(O1, WQ2, PS1, PQ1, WQ1, g1, be1,
                                         O2, PS2, PQ2);
  final_k<<<512, 256, 0, stream>>>(O2, x, PS2, PQ2, WQ2, g2, be2, out);
}

// Round 10
// 73.449 us; speedup vs baseline: 1.3412x; 1.3412x over previous
//
#include <hip/hip_runtime.h>

// ResidualBlock2 (AdderNet): two adder-convs + BN + ReLU + residual.
// N=32, C=32, H=W=32, K=3. No multiplies -> no MFMA; pure VALU
// (2 instr per |x-w|; VALU floor 7.7us/conv).
// R10: R9's ci-split tiling (OPW=1024, LDS ~10us/CU/conv) with staging
// fixed: 1024-thr blocks = 4 co-octs x 4 ci-slices over one 4row x 32col
// x-tile staged ONCE (R9 staged it 4x -> 12.4MB HBM latency-bound = the
// real 50us). Division-free stage loops, SoA reduce buffer (stride-1).

#define QSCALE (2.5f / 127.f)

__device__ __forceinline__ float quantf(float w) {
  float v = rintf(w * (1.0f / QSCALE));     // round-half-even = jnp.round
  v = fminf(fmaxf(v, -127.f), 127.f);
  return v * QSCALE;
}

// quantize + pack: WQ[(ci*9+tap)*32 + co] = quant(w[co][ci*9+tap])
__global__ __launch_bounds__(256) void quant_k(const float* __restrict__ w1,
                                               const float* __restrict__ w2,
                                               float* __restrict__ q1,
                                               float* __restrict__ q2) {
  int i = blockIdx.x * 256 + threadIdx.x;
  if (i >= 18432) return;
  const float* w = (i < 9216) ? w1 : w2;
  float* dst = (i < 9216) ? q1 : q2;
  int j = (i < 9216) ? i : i - 9216;
  int co = j / 288;
  int r = j - co * 288;                     // r = ci*9 + tap
  dst[r * 32 + co] = quantf(w[j]);
}

// Grid 256 = 32 n x 8 rowgroups(4 rows). Block 1024 thr = 16 waves.
// wave: oct = wv&3 (co oct*8..+7), slice = wv>>2 (ci slice*8..+7).
// lane l: quad = l>>5 (co sub-quad), p = l&31: row = p>>3, g = p&7
// (cols 4g..4g+3). acc[4 cols][4 co] = 16/lane. 16 waves/CU = 4/SIMD.
template <bool AFFINE>
__global__ __launch_bounds__(1024, 4) void conv_k(
    const float* __restrict__ in,       // [32][32][32][32] conv input
    const float* __restrict__ wq,       // packed [288][32] this conv
    const float* __restrict__ ps_prev,  // [32][256] prev partial sums (or null)
    const float* __restrict__ pq_prev,  // [32][256] prev partial sumsq
    const float* __restrict__ wq_prev,  // packed prev weights (for wb)
    const float* __restrict__ gprev,    // prev gamma
    const float* __restrict__ bprev,    // prev beta
    float* __restrict__ outb,           // raw conv out
    float* __restrict__ ps_out,         // [32][256] idx: co*256 + n*8 + rg
    float* __restrict__ pq_out) {
  // xs = smem[0..6912) : [32 ci][6 rows][36 cols]
  // wls = smem[6912..16128) : flat [288][32]
  // red aliases smem[0..12288) after compute (SoA [48][256])
  __shared__ __align__(16) float smem[16128];      // 64512 B
  __shared__ float r2a[32][8], r2b[32][8], r2c[32][8];
  __shared__ float abuf[32], bbuf[32];

  float* xs = smem;
  float* wls = smem + 6912;

  const int tid = threadIdx.x;
  const int blk = blockIdx.x;
  const int n = blk >> 3, rg = blk & 7;
  const int h0 = rg << 2;

  if (AFFINE) {
    // Redundant per-block BN1 fold: a=g/sqrt(var+eps), b=beta+wb-a*mu.
    if (tid < 256) {
      const int c = tid & 31, ch = tid >> 5;
      float s = 0.f, q = 0.f;
      #pragma unroll 4
      for (int k = 0; k < 32; ++k) {
        s += ps_prev[c * 256 + ch * 32 + k];
        q += pq_prev[c * 256 + ch * 32 + k];
      }
      float wbp = 0.f;
      #pragma unroll 4
      for (int u = 0; u < 36; ++u) wbp += fabsf(wq_prev[(ch * 36 + u) * 32 + c]);
      r2a[c][ch] = s; r2b[c][ch] = q; r2c[c][ch] = wbp;
    }
    __syncthreads();
    if (tid < 32) {
      double S = 0.0, Q = 0.0; float W = 0.f;
      #pragma unroll
      for (int k = 0; k < 8; ++k) {
        S += (double)r2a[tid][k]; Q += (double)r2b[tid][k]; W += r2c[tid][k];
      }
      const double M = 32768.0;
      const double mu = S / M;
      const double var = Q / M - mu * mu;
      const double inv = 1.0 / sqrt(var + 1e-5);
      const double g = (double)gprev[tid];
      abuf[tid] = (float)(g * inv);
      bbuf[tid] = (float)((double)bprev[tid] + (double)(W * (1.f / 288.f)) - g * inv * mu);
    }
    __syncthreads();
  }

  // ---- stage weights: flat float4 copy (coalesced, L2-hot)
  {
    const float4* src = (const float4*)wq;
    float4* dst = (float4*)wls;
    for (int i = tid; i < 2304; i += 1024) dst[i] = src[i];
  }
  // ---- stage x: thread (ci = tid>>5, c = tid&31); 6 rows, division-free.
  {
    const int ci = tid >> 5, c = tid & 31;
    const float av = AFFINE ? abuf[ci] : 0.f;
    const float bv = AFFINE ? bbuf[ci] : 0.f;
    const float* rowp = in + ((n * 32 + ci) * 32) * 32;
    #pragma unroll
    for (int tr = 0; tr < 6; ++tr) {
      const int h = h0 - 1 + tr;
      const int wcol = c - 1;
      float v = 0.f;
      if ((unsigned)h < 32u && (unsigned)wcol < 32u) {
        v = rowp[h * 32 + wcol];
        if (AFFINE) v = fmaxf(fmaf(av, v, bv), 0.f);
      }
      xs[ci * 216 + tr * 36 + c] = v;
      if (c < 4) {
        const int c2 = 32 + c, w2 = 31 + c;     // global col 31..34
        float v2 = 0.f;
        if ((unsigned)h < 32u && w2 < 32) {
          v2 = rowp[h * 32 + w2];
          if (AFFINE) v2 = fmaxf(fmaf(av, v2, bv), 0.f);
        }
        xs[ci * 216 + tr * 36 + c2] = v2;
      }
    }
  }
  __syncthreads();

  const int wv = tid >> 6;
  const int oct = wv & 3, slice = wv >> 2;
  const int l = tid & 63;
  const int quad = l >> 5, p = l & 31;
  const int row = p >> 3, g = p & 7;

  float acc[4][4];
  #pragma unroll
  for (int j = 0; j < 4; ++j)
    #pragma unroll
    for (int k = 0; k < 4; ++k) acc[j][k] = 0.f;

  const float* xpb = xs + row * 36 + 4 * g;
  const float* wpb = wls + oct * 8 + quad * 4;

  #pragma unroll 2
  for (int cc = 0; cc < 8; ++cc) {
    const int ci = slice * 8 + cc;
    const float* xp = xpb + ci * 216;
    float xw[3][6];
    #pragma unroll
    for (int kh = 0; kh < 3; ++kh) {
      const float4 A = *(const float4*)(xp + kh * 36);
      const float2 B = *(const float2*)(xp + kh * 36 + 4);
      xw[kh][0] = A.x; xw[kh][1] = A.y; xw[kh][2] = A.z; xw[kh][3] = A.w;
      xw[kh][4] = B.x; xw[kh][5] = B.y;
    }
    const float* wp = wpb + ci * 288;
    #pragma unroll
    for (int t = 0; t < 9; ++t) {
      const float4 W = *(const float4*)(wp + t * 32);
      const int kh = t / 3, kw = t - kh * 3;
      #pragma unroll
      for (int j = 0; j < 4; ++j) {
        const float xv = xw[kh][j + kw];
        acc[j][0] += fabsf(xv - W.x);
        acc[j][1] += fabsf(xv - W.y);
        acc[j][2] += fabsf(xv - W.z);
        acc[j][3] += fabsf(xv - W.w);
      }
    }
  }
  __syncthreads();   // xs/wls reads done; red may overwrite

  // ---- cross-slice reduce, SoA: red[(s*16 + j*4+k)*256 + oct*64 + l]
  float* red = smem;
  const int lane16 = oct * 64 + l;
  if (slice != 0) {
    const int sb = (slice - 1) * 16;
    #pragma unroll
    for (int j = 0; j < 4; ++j)
      #pragma unroll
      for (int k = 0; k < 4; ++k)
        red[(sb + j * 4 + k) * 256 + lane16] = acc[j][k];
  }
  __syncthreads();

  if (slice == 0) {
    #pragma unroll
    for (int s = 0; s < 3; ++s)
      #pragma unroll
      for (int j = 0; j < 4; ++j)
        #pragma unroll
        for (int k = 0; k < 4; ++k)
          acc[j][k] += red[(s * 16 + j * 4 + k) * 256 + lane16];

    const int h = h0 + row;
    float sv[4], qv[4];
    #pragma unroll
    for (int k = 0; k < 4; ++k) {
      const int co = oct * 8 + quad * 4 + k;
      float4 st;
      st.x = -acc[0][k]; st.y = -acc[1][k]; st.z = -acc[2][k]; st.w = -acc[3][k];
      *(float4*)&outb[((n * 32 + co) * 32 + h) * 32 + 4 * g] = st;
      sv[k] = st.x + st.y + st.z + st.w;
      qv[k] = st.x*st.x + st.y*st.y + st.z*st.z + st.w*st.w;
    }
    #pragma unroll
    for (int d = 1; d < 32; d <<= 1) {
      #pragma unroll
      for (int k = 0; k < 4; ++k) {
        sv[k] += __shfl_xor(sv[k], d);
        qv[k] += __shfl_xor(qv[k], d);
      }
    }
    if (p == 0) {   // lane 0 (quad 0) and lane 32 (quad 1)
      #pragma unroll
      for (int k = 0; k < 4; ++k) {
        const int co = oct * 8 + quad * 4 + k;
        ps_out[co * 256 + n * 8 + rg] = sv[k];
        pq_out[co * 256 + n * 8 + rg] = qv[k];
      }
    }
  }
}

// ---- K4: redundant BN2 fold + relu(a2*o2 + b2 + x) ----
__global__ __launch_bounds__(256) void final_k(
    const float* __restrict__ o2, const float* __restrict__ xres,
    const float* __restrict__ ps, const float* __restrict__ pq,
    const float* __restrict__ wq2, const float* __restrict__ g2,
    const float* __restrict__ b2, float* __restrict__ out) {
  __shared__ float r2a[32][8], r2b[32][8], r2c[32][8];
  __shared__ float abuf[32], bbuf[32];
  const int tid = threadIdx.x;
  const int c = tid & 31, ch = tid >> 5;
  float s = 0.f, q = 0.f;
  #pragma unroll 4
  for (int k = 0; k < 32; ++k) {
    s += ps[c * 256 + ch * 32 + k];
    q += pq[c * 256 + ch * 32 + k];
  }
  float wbp = 0.f;
  #pragma unroll 4
  for (int u = 0; u < 36; ++u) wbp += fabsf(wq2[(ch * 36 + u) * 32 + c]);
  r2a[c][ch] = s; r2b[c][ch] = q; r2c[c][ch] = wbp;
  __syncthreads();
  if (tid < 32) {
    double S = 0.0, Q = 0.0; float W = 0.f;
    #pragma unroll
    for (int k = 0; k < 8; ++k) {
      S += (double)r2a[tid][k]; Q += (double)r2b[tid][k]; W += r2c[tid][k];
    }
    const double M = 32768.0;
    const double mu = S / M;
    const double var = Q / M - mu * mu;
    const double inv = 1.0 / sqrt(var + 1e-5);
    const double g = (double)g2[tid];
    abuf[tid] = (float)(g * inv);
    bbuf[tid] = (float)((double)b2[tid] + (double)(W * (1.f / 288.f)) - g * inv * mu);
  }
  __syncthreads();

  const int base = blockIdx.x * 512;  // float4 units; 512 x 512 = 262144
  for (int i = tid; i < 512; i += 256) {
    const int f4 = base + i;
    const int cc = (f4 >> 8) & 31;
    const float4 o = ((const float4*)o2)[f4];
    const float4 xr = ((const float4*)xres)[f4];
    const float av = abuf[cc], bv = bbuf[cc];
    float4 r;
    r.x = fmaxf(fmaf(av, o.x, bv) + xr.x, 0.f);
    r.y = fmaxf(fmaf(av, o.y, bv) + xr.y, 0.f);
    r.z = fmaxf(fmaf(av, o.z, bv) + xr.z, 0.f);
    r.w = fmaxf(fmaf(av, o.w, bv) + xr.w, 0.f);
    ((float4*)out)[f4] = r;
  }
}

extern "C" void kernel_launch(void* const* d_in, const int* in_sizes, int n_in,
                              void* d_out, int out_size, void* d_ws, size_t ws_size,
                              hipStream_t stream) {
  const float* x   = (const float*)d_in[0];
  const float* w1  = (const float*)d_in[1];
  const float* g1  = (const float*)d_in[2];
  const float* be1 = (const float*)d_in[3];
  const float* w2  = (const float*)d_in[4];
  const float* g2  = (const float*)d_in[5];
  const float* be2 = (const float*)d_in[6];
  float* ws = (float*)d_ws;

  float* WQ1 = ws;                  // 9216  (packed [288][32])
  float* WQ2 = ws + 9216;           // 9216
  float* PS1 = ws + 18432;          // [32][256] = 8192
  float* PQ1 = ws + 26624;          // 8192
  float* PS2 = ws + 34816;          // 8192
  float* PQ2 = ws + 43008;          // 8192
  float* O1  = ws + 51200;          // 1048576 (16B aligned)
  float* O2  = O1 + 1048576;        // 1048576
  float* out = (float*)d_out;

  quant_k<<<72, 256, 0, stream>>>(w1, w2, WQ1, WQ2);
  conv_k<false><<<256, 1024, 0, stream>>>(x, WQ1, nullptr, nullptr, nullptr,
                                          nullptr, nullptr, O1, PS1, PQ1);
  conv_k<true><<<256, 1024, 0, stream>>>(O1, WQ2, PS1, PQ1, WQ1, g1, be1,
                                         O2, PS2, PQ2);
  final_k<<<512, 256, 0, stream>>>(O2, x, PS2, PQ2, WQ2, g2, be2, out);
}

// Round 11
// 67.068 us; speedup vs baseline: 1.4689x; 1.0951x over previous
//
#include <hip/hip_runtime.h>

// ResidualBlock2 (AdderNet): two adder-convs + BN + ReLU + residual.
// N=32, C=32, H=W=32, K=3. No multiplies -> no MFMA; pure VALU
// (2 instr per |x-w|; VALU floor 7.7us/conv).
// R11: R10's ci-split conv (1024-thr blocks, 4 co-octs x 4 ci-slices,
// x staged once, LDS ~21K cyc/CU/conv) + BN partials reverted to
// CHUNK-MAJOR [256][32] layout: R9/R10's co-major [32][256] made every
// BN-fold read a 1KB-stride lane pattern (1 L2 line per lane per iter;
// ~0.5GB line traffic in final_k's 512 redundant folds ~= 15-20us).
// Chunk-major makes all fold reads lane-coalesced (R8-validated).

#define QSCALE (2.5f / 127.f)

__device__ __forceinline__ float quantf(float w) {
  float v = rintf(w * (1.0f / QSCALE));     // round-half-even = jnp.round
  v = fminf(fmaxf(v, -127.f), 127.f);
  return v * QSCALE;
}

// quantize + pack: WQ[(ci*9+tap)*32 + co] = quant(w[co][ci*9+tap])
__global__ __launch_bounds__(256) void quant_k(const float* __restrict__ w1,
                                               const float* __restrict__ w2,
                                               float* __restrict__ q1,
                                               float* __restrict__ q2) {
  int i = blockIdx.x * 256 + threadIdx.x;
  if (i >= 18432) return;
  const float* w = (i < 9216) ? w1 : w2;
  float* dst = (i < 9216) ? q1 : q2;
  int j = (i < 9216) ? i : i - 9216;
  int co = j / 288;
  int r = j - co * 288;                     // r = ci*9 + tap
  dst[r * 32 + co] = quantf(w[j]);
}

// Grid 256 = 32 n x 8 rowgroups(4 rows). Block 1024 thr = 16 waves.
// wave: oct = wv&3 (co oct*8..+7), slice = wv>>2 (ci slice*8..+7).
// lane l: quad = l>>5 (co sub-quad), p = l&31: row = p>>3, g = p&7
// (cols 4g..4g+3). acc[4 cols][4 co] = 16/lane. 16 waves/CU = 4/SIMD.
// Partials ps/pq: CHUNK-MAJOR [256][32], chunk = n*8+rg (coalesced).
template <bool AFFINE>
__global__ __launch_bounds__(1024, 4) void conv_k(
    const float* __restrict__ in,       // [32][32][32][32] conv input
    const float* __restrict__ wq,       // packed [288][32] this conv
    const float* __restrict__ ps_prev,  // [256][32] prev partial sums (or null)
    const float* __restrict__ pq_prev,  // [256][32] prev partial sumsq
    const float* __restrict__ wq_prev,  // packed prev weights (for wb)
    const float* __restrict__ gprev,    // prev gamma
    const float* __restrict__ bprev,    // prev beta
    float* __restrict__ outb,           // raw conv out
    float* __restrict__ ps_out,         // [256][32]
    float* __restrict__ pq_out) {
  // xs = smem[0..6912) : [32 ci][6 rows][36 cols]
  // wls = smem[6912..16128) : flat [288][32]
  // red aliases smem[0..12288) after compute (SoA [48][256])
  __shared__ __align__(16) float smem[16128];      // 64512 B
  __shared__ float r2a[32][8], r2b[32][8], r2c[32][8];
  __shared__ float abuf[32], bbuf[32];

  float* xs = smem;
  float* wls = smem + 6912;

  const int tid = threadIdx.x;
  const int blk = blockIdx.x;
  const int n = blk >> 3, rg = blk & 7;
  const int h0 = rg << 2;

  if (AFFINE) {
    // Redundant per-block BN1 fold: a=g/sqrt(var+eps), b=beta+wb-a*mu.
    // Reads coalesced: lanes c=0..31 hit consecutive floats.
    if (tid < 256) {
      const int c = tid & 31, ch = tid >> 5;
      float s = 0.f, q = 0.f;
      #pragma unroll 4
      for (int k = 0; k < 32; ++k) {
        s += ps_prev[(ch * 32 + k) * 32 + c];
        q += pq_prev[(ch * 32 + k) * 32 + c];
      }
      float wbp = 0.f;
      #pragma unroll 4
      for (int u = 0; u < 36; ++u) wbp += fabsf(wq_prev[(ch * 36 + u) * 32 + c]);
      r2a[c][ch] = s; r2b[c][ch] = q; r2c[c][ch] = wbp;
    }
    __syncthreads();
    if (tid < 32) {
      double S = 0.0, Q = 0.0; float W = 0.f;
      #pragma unroll
      for (int k = 0; k < 8; ++k) {
        S += (double)r2a[tid][k]; Q += (double)r2b[tid][k]; W += r2c[tid][k];
      }
      const double M = 32768.0;
      const double mu = S / M;
      const double var = Q / M - mu * mu;
      const double inv = 1.0 / sqrt(var + 1e-5);
      const double g = (double)gprev[tid];
      abuf[tid] = (float)(g * inv);
      bbuf[tid] = (float)((double)bprev[tid] + (double)(W * (1.f / 288.f)) - g * inv * mu);
    }
    __syncthreads();
  }

  // ---- stage weights: flat float4 copy (coalesced, L2-hot)
  {
    const float4* src = (const float4*)wq;
    float4* dst = (float4*)wls;
    for (int i = tid; i < 2304; i += 1024) dst[i] = src[i];
  }
  // ---- stage x: thread (ci = tid>>5, c = tid&31); 6 rows, division-free.
  {
    const int ci = tid >> 5, c = tid & 31;
    const float av = AFFINE ? abuf[ci] : 0.f;
    const float bv = AFFINE ? bbuf[ci] : 0.f;
    const float* rowp = in + ((n * 32 + ci) * 32) * 32;
    #pragma unroll
    for (int tr = 0; tr < 6; ++tr) {
      const int h = h0 - 1 + tr;
      const int wcol = c - 1;
      float v = 0.f;
      if ((unsigned)h < 32u && (unsigned)wcol < 32u) {
        v = rowp[h * 32 + wcol];
        if (AFFINE) v = fmaxf(fmaf(av, v, bv), 0.f);
      }
      xs[ci * 216 + tr * 36 + c] = v;
      if (c < 4) {
        const int c2 = 32 + c, w2 = 31 + c;     // global col 31..34
        float v2 = 0.f;
        if ((unsigned)h < 32u && w2 < 32) {
          v2 = rowp[h * 32 + w2];
          if (AFFINE) v2 = fmaxf(fmaf(av, v2, bv), 0.f);
        }
        xs[ci * 216 + tr * 36 + c2] = v2;
      }
    }
  }
  __syncthreads();

  const int wv = tid >> 6;
  const int oct = wv & 3, slice = wv >> 2;
  const int l = tid & 63;
  const int quad = l >> 5, p = l & 31;
  const int row = p >> 3, g = p & 7;

  float acc[4][4];
  #pragma unroll
  for (int j = 0; j < 4; ++j)
    #pragma unroll
    for (int k = 0; k < 4; ++k) acc[j][k] = 0.f;

  const float* xpb = xs + row * 36 + 4 * g;
  const float* wpb = wls + oct * 8 + quad * 4;

  #pragma unroll 2
  for (int cc = 0; cc < 8; ++cc) {
    const int ci = slice * 8 + cc;
    const float* xp = xpb + ci * 216;
    float xw[3][6];
    #pragma unroll
    for (int kh = 0; kh < 3; ++kh) {
      const float4 A = *(const float4*)(xp + kh * 36);
      const float2 B = *(const float2*)(xp + kh * 36 + 4);
      xw[kh][0] = A.x; xw[kh][1] = A.y; xw[kh][2] = A.z; xw[kh][3] = A.w;
      xw[kh][4] = B.x; xw[kh][5] = B.y;
    }
    const float* wp = wpb + ci * 288;
    #pragma unroll
    for (int t = 0; t < 9; ++t) {
      const float4 W = *(const float4*)(wp + t * 32);
      const int kh = t / 3, kw = t - kh * 3;
      #pragma unroll
      for (int j = 0; j < 4; ++j) {
        const float xv = xw[kh][j + kw];
        acc[j][0] += fabsf(xv - W.x);
        acc[j][1] += fabsf(xv - W.y);
        acc[j][2] += fabsf(xv - W.z);
        acc[j][3] += fabsf(xv - W.w);
      }
    }
  }
  __syncthreads();   // xs/wls reads done; red may overwrite

  // ---- cross-slice reduce, SoA: red[(s*16 + j*4+k)*256 + oct*64 + l]
  float* red = smem;
  const int lane16 = oct * 64 + l;
  if (slice != 0) {
    const int sb = (slice - 1) * 16;
    #pragma unroll
    for (int j = 0; j < 4; ++j)
      #pragma unroll
      for (int k = 0; k < 4; ++k)
        red[(sb + j * 4 + k) * 256 + lane16] = acc[j][k];
  }
  __syncthreads();

  if (slice == 0) {
    #pragma unroll
    for (int s = 0; s < 3; ++s)
      #pragma unroll
      for (int j = 0; j < 4; ++j)
        #pragma unroll
        for (int k = 0; k < 4; ++k)
          acc[j][k] += red[(s * 16 + j * 4 + k) * 256 + lane16];

    const int h = h0 + row;
    float sv[4], qv[4];
    #pragma unroll
    for (int k = 0; k < 4; ++k) {
      const int co = oct * 8 + quad * 4 + k;
      float4 st;
      st.x = -acc[0][k]; st.y = -acc[1][k]; st.z = -acc[2][k]; st.w = -acc[3][k];
      *(float4*)&outb[((n * 32 + co) * 32 + h) * 32 + 4 * g] = st;
      sv[k] = st.x + st.y + st.z + st.w;
      qv[k] = st.x*st.x + st.y*st.y + st.z*st.z + st.w*st.w;
    }
    #pragma unroll
    for (int d = 1; d < 32; d <<= 1) {
      #pragma unroll
      for (int k = 0; k < 4; ++k) {
        sv[k] += __shfl_xor(sv[k], d);
        qv[k] += __shfl_xor(qv[k], d);
      }
    }
    if (p == 0) {   // lane 0 (quad 0) and lane 32 (quad 1): adjacent float4s
      const int chunk = n * 8 + rg;
      float4 s4; s4.x = sv[0]; s4.y = sv[1]; s4.z = sv[2]; s4.w = sv[3];
      float4 q4; q4.x = qv[0]; q4.y = qv[1]; q4.z = qv[2]; q4.w = qv[3];
      ((float4*)(ps_out + chunk * 32))[oct * 2 + quad] = s4;
      ((float4*)(pq_out + chunk * 32))[oct * 2 + quad] = q4;
    }
  }
}

// ---- K4: redundant BN2 fold + relu(a2*o2 + b2 + x) ----
__global__ __launch_bounds__(256) void final_k(
    const float* __restrict__ o2, const float* __restrict__ xres,
    const float* __restrict__ ps, const float* __restrict__ pq,
    const float* __restrict__ wq2, const float* __restrict__ g2,
    const float* __restrict__ b2, float* __restrict__ out) {
  __shared__ float r2a[32][8], r2b[32][8], r2c[32][8];
  __shared__ float abuf[32], bbuf[32];
  const int tid = threadIdx.x;
  const int c = tid & 31, ch = tid >> 5;
  float s = 0.f, q = 0.f;
  #pragma unroll 4
  for (int k = 0; k < 32; ++k) {
    s += ps[(ch * 32 + k) * 32 + c];
    q += pq[(ch * 32 + k) * 32 + c];
  }
  float wbp = 0.f;
  #pragma unroll 4
  for (int u = 0; u < 36; ++u) wbp += fabsf(wq2[(ch * 36 + u) * 32 + c]);
  r2a[c][ch] = s; r2b[c][ch] = q; r2c[c][ch] = wbp;
  __syncthreads();
  if (tid < 32) {
    double S = 0.0, Q = 0.0; float W = 0.f;
    #pragma unroll
    for (int k = 0; k < 8; ++k) {
      S += (double)r2a[tid][k]; Q += (double)r2b[tid][k]; W += r2c[tid][k];
    }
    const double M = 32768.0;
    const double mu = S / M;
    const double var = Q / M - mu * mu;
    const double inv = 1.0 / sqrt(var + 1e-5);
    const double g = (double)g2[tid];
    abuf[tid] = (float)(g * inv);
    bbuf[tid] = (float)((double)b2[tid] + (double)(W * (1.f / 288.f)) - g * inv * mu);
  }
  __syncthreads();

  const int base = blockIdx.x * 512;  // float4 units; 512 x 512 = 262144
  for (int i = tid; i < 512; i += 256) {
    const int f4 = base + i;
    const int cc = (f4 >> 8) & 31;
    const float4 o = ((const float4*)o2)[f4];
    const float4 xr = ((const float4*)xres)[f4];
    const float av = abuf[cc], bv = bbuf[cc];
    float4 r;
    r.x = fmaxf(fmaf(av, o.x, bv) + xr.x, 0.f);
    r.y = fmaxf(fmaf(av, o.y, bv) + xr.y, 0.f);
    r.z = fmaxf(fmaf(av, o.z, bv) + xr.z, 0.f);
    r.w = fmaxf(fmaf(av, o.w, bv) + xr.w, 0.f);
    ((float4*)out)[f4] = r;
  }
}

extern "C" void kernel_launch(void* const* d_in, const int* in_sizes, int n_in,
                              void* d_out, int out_size, void* d_ws, size_t ws_size,
                              hipStream_t stream) {
  const float* x   = (const float*)d_in[0];
  const float* w1  = (const float*)d_in[1];
  const float* g1  = (const float*)d_in[2];
  const float* be1 = (const float*)d_in[3];
  const float* w2  = (const float*)d_in[4];
  const float* g2  = (const float*)d_in[5];
  const float* be2 = (const float*)d_in[6];
  float* ws = (float*)d_ws;

  float* WQ1 = ws;                  // 9216  (packed [288][32])
  float* WQ2 = ws + 9216;           // 9216
  float* PS1 = ws + 18432;          // [256][32] = 8192
  float* PQ1 = ws + 26624;          // 8192
  float* PS2 = ws + 34816;          // 8192
  float* PQ2 = ws + 43008;          // 8192
  float* O1  = ws + 51200;          // 1048576 (16B aligned)
  float* O2  = O1 + 1048576;        // 1048576
  float* out = (float*)d_out;

  quant_k<<<72, 256, 0, stream>>>(w1, w2, WQ1, WQ2);
  conv_k<false><<<256, 1024, 0, stream>>>(x, WQ1, nullptr, nullptr, nullptr,
                                          nullptr, nullptr, O1, PS1, PQ1);
  conv_k<true><<<256, 1024, 0, stream>>>(O1, WQ2, PS1, PQ1, WQ1, g1, be1,
                                         O2, PS2, PQ2);
  final_k<<<512, 256, 0, stream>>>(O2, x, PS2, PQ2, WQ2, g2, be2, out);
}